// Round 2
// baseline (253.213 us; speedup 1.0000x reference)
//
#include <hip/hip_runtime.h>
#include <cstdint>
#include <cstddef>

// Problem constants (reference: B=4, T=4096, E=1024, M=E/2=512)
#define Tdim 4096
#define Bdim 4
#define Edim 1024
#define Mdim 512
#define EPSF 1e-6f

typedef __bf16 bf16x8 __attribute__((ext_vector_type(8)));
typedef float f32x4 __attribute__((ext_vector_type(4)));

// float -> bf16 bits, round-to-nearest-even (used in extract path)
__device__ __forceinline__ unsigned short f2bf(float f) {
  union { float f; unsigned int u; } a; a.f = f;
  unsigned int r = a.u + 0x7fffu + ((a.u >> 16) & 1u);
  return (unsigned short)(r >> 16);
}

// pack two f32 -> bf16x2 (round-half-up; 0.5-ulp bound, ties negligible here)
__device__ __forceinline__ unsigned int pack_bf16(float a, float b) {
  union { float f; unsigned int u; } ua, ub; ua.f = a; ub.f = b;
  // dst bytes [0,1,2,3] = [a.b2, a.b3, b.b2, b.b3]
  return __builtin_amdgcn_perm(ub.u + 0x8000u, ua.u + 0x8000u, 0x07060302u);
}

// bump kernel g(u) = exp(1 - 1/(1-u^2+eps)); reference's u>=1-EPS clamp can
// never fire for j<=T-1 (u_max = 1 - 1/horizon), so it is omitted.
__device__ __forceinline__ float kernel_g(float dj, float inv_h) {
  float u = fminf(dj * inv_h, 1.0f - EPSF);
  return __expf(1.0f - 1.0f / (1.0f - u * u + EPSF));
}

typedef void __attribute__((address_space(1)))* gas1;
typedef void __attribute__((address_space(3)))* las3;
// async global->LDS, 16B per lane; LDS dest = wave-uniform base + lane*16
__device__ __forceinline__ void load_lds16(const void* g, void* l) {
  __builtin_amdgcn_global_load_lds((gas1)(g), (las3)(l), 16, 0, 0);
}

// ---------------- fused prep: K rows (rowsum+normalize+pack) AND Xc transpose --------
// grid 8192 x 256. Blocks [0,4096): K row i = blockIdx.x (compute g into LDS,
// block-reduce sum, scale, pack bf16, write row from the 128-ALIGNED tile start
// (i & ~127) onward -- the GEMM's i-tiles are 128 wide and never read k below
// their tile start; columns below the tile start are never read so the
// lower-triangle writes there are skipped (-~12 MiB HBM). NOTE: guard must
// match the GEMM tile width (R1 bug class: 64-aligned guard + 128-wide tiles
// would leave garbage in [i&~127, i&~63) for upper-half rows).
// Blocks [4096,8192): extract tile -> XcT[b][m][j] = bf16(x[b][j][2m]).
__global__ __launch_bounds__(256) void prep_kernel(const float* __restrict__ x,
                                                   unsigned short* __restrict__ Kmat,
                                                   unsigned short* __restrict__ XcT) {
  __shared__ float smem[4104];  // krow: [0..4095]=g, [4096..4099]=wave sums
  const int tid = threadIdx.x;
  const int id = blockIdx.x;
  if (id < Tdim) {
    // ---- K row i ----
    const int i = id;
    const float inv_h = __fdividef(1.0f, (float)(Tdim - i));
    float s = 0.0f;
    for (int j = i + tid; j < Tdim; j += 256) {
      const float g = kernel_g((float)(j - i), inv_h);
      smem[j] = g;
      s += g;
    }
#pragma unroll
    for (int off = 32; off; off >>= 1) s += __shfl_down(s, off);
    if ((tid & 63) == 0) smem[4096 + (tid >> 6)] = s;
    __syncthreads();  // g[] complete + wave sums visible
    const float inv_s = __fdividef(
        1.0f, fmaxf(smem[4096] + smem[4097] + smem[4098] + smem[4099], EPSF));
    unsigned short* row = Kmat + (size_t)i * Tdim;
    const int q0 = (i >> 7) << 4;  // first uint4 chunk of the 128-aligned tile
    for (int q = q0 + tid; q < 512; q += 256) {  // uint4 chunks from tile start
      const int j8 = q * 8;
      float v[8];
#pragma unroll
      for (int k = 0; k < 8; ++k) {
        const int j = j8 + k;
        v[k] = (j >= i) ? smem[j] * inv_s : 0.0f;  // guard before use: no uninit read
      }
      uint4 pk;
      pk.x = pack_bf16(v[0], v[1]);
      pk.y = pack_bf16(v[2], v[3]);
      pk.z = pack_bf16(v[4], v[5]);
      pk.w = pack_bf16(v[6], v[7]);
      *reinterpret_cast<uint4*>(&row[j8]) = pk;
    }
  } else {
    // ---- extract tile: 64 j x 32 m ----
    const int eid = id - Tdim;
    const int j0 = (eid & 63) * 64;
    const int m0 = ((eid >> 6) & 15) * 32;
    const int b  = eid >> 10;
    unsigned short* Ls = reinterpret_cast<unsigned short*>(smem);  // [32][68]
    const int q = tid & 15;        // float4 chunk along e
    const int jbase = tid >> 4;    // 0..15
#pragma unroll
    for (int it = 0; it < 4; ++it) {
      const int jj = jbase + it * 16;
      const size_t off = ((size_t)(b * Tdim + j0 + jj)) * Edim + 2 * m0 + 4 * q;
      const float4 v = *reinterpret_cast<const float4*>(&x[off]);
      Ls[(2 * q) * 68 + jj]     = f2bf(v.x);   // even channel of m0+2q
      Ls[(2 * q + 1) * 68 + jj] = f2bf(v.z);   // even channel of m0+2q+1
    }
    __syncthreads();
    const int ch = tid & 15;
    const int mb = tid >> 4;
#pragma unroll
    for (int it = 0; it < 2; ++it) {
      const int m = mb + it * 16;
      ushort4 uv;
      uv.x = Ls[m * 68 + 4 * ch];
      uv.y = Ls[m * 68 + 4 * ch + 1];
      uv.z = Ls[m * 68 + 4 * ch + 2];
      uv.w = Ls[m * 68 + 4 * ch + 3];
      *reinterpret_cast<ushort4*>(
          &XcT[((size_t)(b * Mdim + m0 + m)) * Tdim + j0 + 4 * ch]) = uv;
    }
  }
}

// ---------------- GEMM: phi[b,i,m] = K[i,:] @ Xc[b,:,m], fused output write --------
// C-tile 128(i) x 128(m), 4 waves (each 64x64 = 4x4 frags of 16x16x32).
// BK=32, FOUR LDS buffers (4 x 16 KiB = 64 KiB -> 2 blocks/CU), prefetch
// DEPTH 2 with counted vmcnt (T3+T4): per iter issue STAGE(t+2), then
// `s_waitcnt vmcnt(8)` (tiles t+1,t+2 = 8 loads/wave stay IN FLIGHT, never
// drained to 0), raw s_barrier, sched_barrier(0), then ds_read+MFMA on buf
// t&3. Tile t's loads age TWO compute phases before use, vs the old
// __syncthreads() structure whose vmcnt(0) drain gave them only one short
// phase (the measured ~2600 cyc/iter wall at MfmaUtil 17%).
// Overwrite safety: STAGE(t+2) writes buf (t-2)&3, whose reads finished
// before barrier t-1 for ALL waves -> one barrier per iter is race-free.
// Tail: always issue exactly 4 loads/wave/iter (source j clamped to the last
// valid k-tile, dead buffer) so the vmcnt count stays uniform & branch-free.
// LDS layout is K-MAJOR [kc][row] (physical slot g=n*64+lane -> kc=g>>7,
// row=g&127; source address per-lane, LDS dest linear): fragment ds_read_b128
// is 256B-contiguous per 16-lane group -> conflict-free, no XOR swizzle.
// Work distribution: static anti-length pairing (R0, known-ideal FETCH):
// CU c owns blocks {c, c+256}; iteration totals (128-4p)+(128-4(31-p))=132,
// exactly uniform; the 16 blocks sharing Kmat rows are adjacent ids (L2/L3).
// Epilogue computes softplus(graw) inline.
__global__ __launch_bounds__(256) void gemm_kernel(
    const unsigned short* __restrict__ Kmat,
    const unsigned short* __restrict__ XcT,
    const float* __restrict__ x,
    const float* __restrict__ graw,
    float* __restrict__ out) {
  __shared__ unsigned short As[4][128 * 32];  // k-major [kc][row] per buffer
  __shared__ unsigned short Bs[4][128 * 32];
  const int id = blockIdx.x;           // 0..511
  int p;
  if (id < 256) p = id >> 4;
  else          p = 31 - ((id - 256) >> 4);
  const int mb = id & 15;
  const int i0 = p * 128;
  const int m0 = (mb & 3) * 128;
  const int b  = mb >> 2;
  const int tid = threadIdx.x;
  const int w = tid >> 6;
  const int l = tid & 63;
  const int wr = w >> 1, wc = w & 1;
  const unsigned short* Arow = Kmat + (size_t)i0 * Tdim;
  const unsigned short* Brow = XcT + ((size_t)b * Mdim + m0) * Tdim;

  // staging: 8 A-instrs + 8 B-instrs per k-tile; wave w issues A{2w,2w+1} and
  // B{2w,2w+1} -> 4 loads/wave/tile (the vmcnt unit). instr n, lane l:
  // g = n*64+l, kc = g>>7, row = g&127; source = row*Tdim + jt + kc*8.
  const int g0 = (2 * w) * 64 + l;
  const int g1 = g0 + 64;
  const size_t aoff0 = (size_t)(g0 & 127) * Tdim + (g0 >> 7) * 8;
  const size_t aoff1 = (size_t)(g1 & 127) * Tdim + (g1 >> 7) * 8;
  f32x4 acc[4][4] = {};

#define STAGE(bufi, jt)                                                     \
  do {                                                                      \
    load_lds16(Arow + aoff0 + (jt), &As[(bufi)][(2 * w) * 512]);            \
    load_lds16(Arow + aoff1 + (jt), &As[(bufi)][(2 * w + 1) * 512]);        \
    load_lds16(Brow + aoff0 + (jt), &Bs[(bufi)][(2 * w) * 512]);            \
    load_lds16(Brow + aoff1 + (jt), &Bs[(bufi)][(2 * w + 1) * 512]);        \
  } while (0)

  const int n = (Tdim - i0) >> 5;  // 128 - 4p k-tiles (>= 4 always)
  STAGE(0, i0);
  STAGE(1, i0 + 32);

  const int lr16 = l & 15;
  const int kq = l >> 4;  // 0..3: which 16B k-chunk this lane's fragment holds
  int jt = i0;
  for (int t = 0; t < n; ++t, jt += 32) {
    // prefetch tile t+2 (clamped dummy at the tail keeps vmcnt uniform)
    const int jc = (jt + 64 <= Tdim - 32) ? (jt + 64) : (Tdim - 32);
    STAGE((t + 2) & 3, jc);
    asm volatile("s_waitcnt vmcnt(8)" ::: "memory");  // tile t resident (this wave)
    __builtin_amdgcn_s_barrier();                     // ...and for all waves
    __builtin_amdgcn_sched_barrier(0);                // no ds_read hoisted above
    const int buf = t & 3;
    bf16x8 af[4], bfr[4];
#pragma unroll
    for (int r = 0; r < 4; ++r)
      af[r] = *reinterpret_cast<const bf16x8*>(
          &As[buf][(kq * 128 + wr * 64 + r * 16 + lr16) * 8]);
#pragma unroll
    for (int c = 0; c < 4; ++c)
      bfr[c] = *reinterpret_cast<const bf16x8*>(
          &Bs[buf][(kq * 128 + wc * 64 + c * 16 + lr16) * 8]);
#pragma unroll
    for (int r = 0; r < 4; ++r)
#pragma unroll
      for (int c = 0; c < 4; ++c)
        acc[r][c] = __builtin_amdgcn_mfma_f32_16x16x32_bf16(af[r], bfr[c], acc[r][c], 0, 0, 0);
  }
#undef STAGE

  // fused epilogue: C/D layout col=lane&15 (m), row=(lane>>4)*4+reg (i).
  // out even = x even (exact fp32 passthrough), odd = phi*softplus(graw[m]).
  const int lr = l & 15;
  const int lq = l >> 4;
  float gm[4];
#pragma unroll
  for (int c = 0; c < 4; ++c) {
    const float v = graw[m0 + wc * 64 + c * 16 + lr];
    gm[c] = fmaxf(v, 0.0f) + __logf(1.0f + __expf(-fabsf(v)));  // stable softplus
  }
#pragma unroll
  for (int r = 0; r < 4; ++r) {
    const int ii = i0 + wr * 64 + r * 16 + lq * 4;
#pragma unroll
    for (int c = 0; c < 4; ++c) {
      const int m = m0 + wc * 64 + c * 16 + lr;
#pragma unroll
      for (int v = 0; v < 4; ++v) {
        const size_t o = ((size_t)(b * Tdim + ii + v)) * Edim + 2 * m;
        const float2 xv = *reinterpret_cast<const float2*>(&x[o]);
        float2 res;
        res.x = xv.x;
        res.y = acc[r][c][v] * gm[c];
        *reinterpret_cast<float2*>(&out[o]) = res;
      }
    }
  }
}

// ---------------- slow-but-correct fallback (only if ws too small) ----------------
__global__ __launch_bounds__(256) void fallback_kernel(const float* __restrict__ x,
                                                       const float* __restrict__ graw,
                                                       float* __restrict__ out) {
  const int i = blockIdx.x, b = blockIdx.y, tid = threadIdx.x;
  const float inv_h = 1.0f / (float)(Tdim - i);
  float s = 0.0f;
  for (int j = i + tid; j < Tdim; j += 256)
    s += kernel_g((float)(j - i), inv_h);
#pragma unroll
  for (int off = 32; off; off >>= 1) s += __shfl_down(s, off);
  __shared__ float red[4];
  __shared__ float sinv_sh;
  if ((tid & 63) == 0) red[tid >> 6] = s;
  __syncthreads();
  if (tid == 0) sinv_sh = 1.0f / (red[0] + red[1] + red[2] + red[3]);
  __syncthreads();
  const float sinv = sinv_sh;
  const float* xb = x + (size_t)b * Tdim * Edim;
  float a0 = 0.0f, a1 = 0.0f;
  const int m0 = tid, m1 = tid + 256;
  for (int j = i; j < Tdim; ++j) {
    const float wgt = kernel_g((float)(j - i), inv_h);
    const float* xr = xb + (size_t)j * Edim;
    a0 += wgt * xr[2 * m0];
    a1 += wgt * xr[2 * m1];
  }
  const float v0 = graw[m0], v1 = graw[m1];
  const float g0 = fmaxf(v0, 0.0f) + log1pf(__expf(-fabsf(v0)));
  const float g1 = fmaxf(v1, 0.0f) + log1pf(__expf(-fabsf(v1)));
  const size_t o = ((size_t)(b * Tdim + i)) * Edim;
  const float* xi = xb + (size_t)i * Edim;
  out[o + 2 * m0]     = xi[2 * m0];
  out[o + 2 * m0 + 1] = a0 * sinv * g0;
  out[o + 2 * m1]     = xi[2 * m1];
  out[o + 2 * m1 + 1] = a1 * sinv * g1;
}

extern "C" void kernel_launch(void* const* d_in, const int* in_sizes, int n_in,
                              void* d_out, int out_size, void* d_ws, size_t ws_size,
                              hipStream_t stream) {
  const float* x = (const float*)d_in[0];
  // d_in[1] is the triu mask: always upper-triangular by construction; folded analytically.
  const float* gate_raw = (const float*)d_in[2];
  float* out = (float*)d_out;

  const size_t XcT_bytes = (size_t)Bdim * Mdim * Tdim * 2;  // 16 MiB
  const size_t K_bytes   = (size_t)Tdim * Tdim * 2;         // 32 MiB
  const size_t need = XcT_bytes + K_bytes;

  if (ws_size < need) {
    fallback_kernel<<<dim3(Tdim, Bdim), 256, 0, stream>>>(x, gate_raw, out);
    return;
  }

  char* ws = (char*)d_ws;
  unsigned short* XcT  = (unsigned short*)ws;
  unsigned short* Kmat = (unsigned short*)(ws + XcT_bytes);

  prep_kernel<<<dim3(2 * Tdim), 256, 0, stream>>>(x, Kmat, XcT);
  gemm_kernel<<<dim3(512), 256, 0, stream>>>(Kmat, XcT, x, gate_raw, out);
}

// Round 3
// 227.513 us; speedup vs baseline: 1.1130x; 1.1130x over previous
//
#include <hip/hip_runtime.h>
#include <cstdint>
#include <cstddef>

// Problem constants (reference: B=4, T=4096, E=1024, M=E/2=512)
#define Tdim 4096
#define Bdim 4
#define Edim 1024
#define Mdim 512
#define EPSF 1e-6f
#define NTILES 1056  // sum over p of (64-2p) = S(32), panels store only k>=i0

typedef __bf16 bf16x8 __attribute__((ext_vector_type(8)));
typedef float f32x4 __attribute__((ext_vector_type(4)));

// S(p) = number of k64-tiles in panels [0,p) = p*(65-p)
__host__ __device__ __forceinline__ int panel_start(int p) { return p * (65 - p); }

// float -> bf16 bits, round-to-nearest-even (used in extract path)
__device__ __forceinline__ unsigned short f2bf(float f) {
  union { float f; unsigned int u; } a; a.f = f;
  unsigned int r = a.u + 0x7fffu + ((a.u >> 16) & 1u);
  return (unsigned short)(r >> 16);
}

// pack two f32 -> bf16x2 (round-half-up; 0.5-ulp bound, ties negligible here)
__device__ __forceinline__ unsigned int pack_bf16(float a, float b) {
  union { float f; unsigned int u; } ua, ub; ua.f = a; ub.f = b;
  // dst bytes [0,1,2,3] = [a.b2, a.b3, b.b2, b.b3]
  return __builtin_amdgcn_perm(ub.u + 0x8000u, ua.u + 0x8000u, 0x07060302u);
}

// bump kernel g(u) = exp(1 - 1/(1-u^2+eps)); reference's u>=1-EPS clamp can
// never fire for j<=T-1 (u_max = 1 - 1/horizon), so it is omitted.
__device__ __forceinline__ float kernel_g(float dj, float inv_h) {
  float u = fminf(dj * inv_h, 1.0f - EPSF);
  return __expf(1.0f - 1.0f / (1.0f - u * u + EPSF));
}

typedef void __attribute__((address_space(1)))* gas1;
typedef void __attribute__((address_space(3)))* las3;
// async global->LDS, 16B per lane; LDS dest = wave-uniform base + lane*16
__device__ __forceinline__ void load_lds16(const void* g, void* l) {
  __builtin_amdgcn_global_load_lds((gas1)(g), (las3)(l), 16, 0, 0);
}

// ---------------- prep: row sums (inv_s) AND Xc transpose ----------------
// grid 8192 x 256. Blocks [0,4096): rowsum only -- compute sum_j g(i,j),
// write inv_s[i] = 1/max(sum,eps). (K packing moved to packK_kernel, which
// owns contiguous 16-KB fragment tiles -> coalesced writes; one-row-per-block
// can't write the fragment layout coalesced.) Blocks [4096,8192): extract
// tile -> XcT[b][m][j] = bf16(x[b][j][2m]) (unchanged, R0-verified).
__global__ __launch_bounds__(256) void prep_kernel(const float* __restrict__ x,
                                                   float* __restrict__ inv_s,
                                                   unsigned short* __restrict__ XcT) {
  __shared__ float smem[1104];  // extract: [0..1087] as ushort[32][68]; rowsum: [1088..1091]
  const int tid = threadIdx.x;
  const int id = blockIdx.x;
  if (id < Tdim) {
    // ---- rowsum for K row i (same summation order as R0 -> identical bits) ----
    const int i = id;
    const float inv_h = __fdividef(1.0f, (float)(Tdim - i));
    float s = 0.0f;
    for (int j = i + tid; j < Tdim; j += 256)
      s += kernel_g((float)(j - i), inv_h);
#pragma unroll
    for (int off = 32; off; off >>= 1) s += __shfl_down(s, off);
    if ((tid & 63) == 0) smem[1088 + (tid >> 6)] = s;
    __syncthreads();
    if (tid == 0)
      inv_s[i] = __fdividef(
          1.0f, fmaxf(smem[1088] + smem[1089] + smem[1090] + smem[1091], EPSF));
  } else {
    // ---- extract tile: 64 j x 32 m ----
    const int eid = id - Tdim;
    const int j0 = (eid & 63) * 64;
    const int m0 = ((eid >> 6) & 15) * 32;
    const int b  = eid >> 10;
    unsigned short* Ls = reinterpret_cast<unsigned short*>(smem);  // [32][68]
    const int q = tid & 15;        // float4 chunk along e
    const int jbase = tid >> 4;    // 0..15
#pragma unroll
    for (int it = 0; it < 4; ++it) {
      const int jj = jbase + it * 16;
      const size_t off = ((size_t)(b * Tdim + j0 + jj)) * Edim + 2 * m0 + 4 * q;
      const float4 v = *reinterpret_cast<const float4*>(&x[off]);
      Ls[(2 * q) * 68 + jj]     = f2bf(v.x);   // even channel of m0+2q
      Ls[(2 * q + 1) * 68 + jj] = f2bf(v.z);   // even channel of m0+2q+1
    }
    __syncthreads();
    const int ch = tid & 15;
    const int mb = tid >> 4;
#pragma unroll
    for (int it = 0; it < 2; ++it) {
      const int m = mb + it * 16;
      ushort4 uv;
      uv.x = Ls[m * 68 + 4 * ch];
      uv.y = Ls[m * 68 + 4 * ch + 1];
      uv.z = Ls[m * 68 + 4 * ch + 2];
      uv.w = Ls[m * 68 + 4 * ch + 3];
      *reinterpret_cast<ushort4*>(
          &XcT[((size_t)(b * Mdim + m0 + m)) * Tdim + j0 + 4 * ch]) = uv;
    }
  }
}

// ---------------- packK: K in MFMA-fragment order ----------------
// Kswz stores, per panel p (i-tile of 128 rows) and k64-tile jt (k >= i0
// only), 16 blocks of 1 KB indexed ((h*4+r)*2+kk), h=row-half, r=16-row
// group, kk=k32 half. Within a block, lane l = kq*16+lr16 holds 16 B =
// row (h*64+r*16+lr16), k-chunk (kk*4+kq)*8 -- EXACTLY the A-fragment of
// v_mfma_f32_16x16x32_bf16 (lane l <- A[r16+(l&15)][kk*32+(l>>4)*8]), so
// the gemm fetches A with one coalesced global_load_dwordx4 per fragment,
// NO LDS. (R0's K-loop was LDS-throughput-bound: 64 ds_read_b128 x 12cyc
// = 768 cyc/iter vs 620 cyc MFMA; removing the A side drops LDS to ~512.)
// One block per (p,jt): thread t writes 4 x 16 B at byte offsets
// (ss*256+t)*16 -> wave-contiguous 1-KB stores, fully coalesced.
__global__ __launch_bounds__(256) void packK_kernel(const float* __restrict__ inv_s,
                                                    unsigned short* __restrict__ Kswz) {
  const int id = blockIdx.x;  // 0..NTILES-1
  int p = 0;
  while (id >= (p + 1) * (64 - p)) ++p;   // S(p+1) = (p+1)*(64-p)
  const int jt = id - panel_start(p);
  const int i0 = p * 128;
  const int jb0 = i0 + jt * 64;
  unsigned short* dst = Kswz + (size_t)id * 8192;  // 16 KB per (p,jt) tile
  const int tid = threadIdx.x;
#pragma unroll
  for (int ss = 0; ss < 4; ++ss) {
    const int G = ss * 256 + tid;          // chunk index 0..1023
    const int lane = G & 63;
    const int kk = (G >> 6) & 1;
    const int r  = (G >> 7) & 3;
    const int h  = G >> 9;
    const int li = h * 64 + r * 16 + (lane & 15);
    const int i  = i0 + li;
    const float inv_h = __fdividef(1.0f, (float)(Tdim - i));
    const float sinv = inv_s[i];
    const int jb = jb0 + (kk * 4 + (lane >> 4)) * 8;
    float v[8];
#pragma unroll
    for (int e = 0; e < 8; ++e) {
      const int j = jb + e;
      v[e] = (j >= i) ? kernel_g((float)(j - i), inv_h) * sinv : 0.0f;
    }
    uint4 pk;
    pk.x = pack_bf16(v[0], v[1]);
    pk.y = pack_bf16(v[2], v[3]);
    pk.z = pack_bf16(v[4], v[5]);
    pk.w = pack_bf16(v[6], v[7]);
    *reinterpret_cast<uint4*>(&dst[(size_t)G * 8]) = pk;
  }
}

// ---------------- GEMM: phi[b,i,m] = K[i,:] @ Xc[b,:,m], fused output write --------
// R0 structure (verified best: BK=64, double-buffered B staging via
// global_load_lds + XOR swizzle, ONE __syncthreads per iter, anti-length
// pairing, 128x128 C-tile, 4 waves, 4x4 frags of 16x16x32) with ONE change:
// the A operand comes from Kswz via coalesced global->VGPR loads instead of
// LDS. LDS now holds only B (2 x 16 KB): per block-iter LDS traffic drops
// 1024 -> ~512 cyc, below the 620-cyc MFMA pipe -> MFMA-bound.
// Ordering: A-loads are issued BEFORE the B global_load_lds (pinned by one
// sched_barrier(0)) so the compiler's wait for A is vmcnt(4) -- the 4
// younger staging loads stay in flight -- instead of a vmcnt(0) drain.
__global__ __launch_bounds__(256) void gemm_kernel(
    const unsigned short* __restrict__ Kswz,
    const unsigned short* __restrict__ XcT,
    const float* __restrict__ x,
    const float* __restrict__ graw,
    float* __restrict__ out) {
  __shared__ unsigned short Bs[2][128 * 64];  // XcT rows m0.., swizzled 16B slots
  const int id = blockIdx.x;           // 0..511
  int p;
  if (id < 256) p = id >> 4;
  else          p = 31 - ((id - 256) >> 4);
  const int mb = id & 15;
  const int i0 = p * 128;
  const int m0 = (mb & 3) * 128;
  const int b  = mb >> 2;
  const int tid = threadIdx.x;
  const int w = tid >> 6;
  const int l = tid & 63;
  const int wr = w >> 1, wc = w & 1;
  const unsigned short* Brow = XcT + ((size_t)b * Mdim + m0) * Tdim;
  const int srow  = l >> 3;                   // row within 8-row group
  const int sslot = l & 7;                    // linear 16B slot this lane fills
  const int schunk = (sslot ^ srow) * 8;      // swizzled source chunk (bf16 units)
  // A panel base for this wave's row-half and lane (units: shorts).
  // Fragment (r,kk) of k-tile t is at Apan + t*8192 + (r*2+kk)*512.
  const unsigned short* Apan =
      Kswz + (size_t)panel_start(p) * 8192 + (size_t)(wr * 8) * 512 + (size_t)l * 8;

  f32x4 acc[4][4] = {};
  const int n = (Tdim - i0) >> 6;  // 64 - 2p k64-tiles

  // preload B tile 0 into buffer 0
#pragma unroll
  for (int t = 0; t < 4; ++t) {
    const int rr = (w * 4 + t) * 8 + srow;
    load_lds16(Brow + (size_t)rr * Tdim + (i0 + schunk), &Bs[0][(w * 4 + t) * 512]);
  }

  const int lr16 = l & 15;
  const int kq = l >> 4;  // 0..3: which 16B chunk quarter of the k-dim
  int cur = 0;
  for (int t = 0; t < n; ++t, cur ^= 1) {
    __syncthreads();  // vmcnt(0) drain: B tile `cur` resident; prev reads done
    // A fragments for THIS tile: 8 coalesced 16B/lane loads -> VGPR
    const unsigned short* At = Apan + (size_t)t * 8192;
    bf16x8 af[2][4];
#pragma unroll
    for (int r = 0; r < 4; ++r) {
      af[0][r] = *reinterpret_cast<const bf16x8*>(At + (r * 2 + 0) * 512);
      af[1][r] = *reinterpret_cast<const bf16x8*>(At + (r * 2 + 1) * 512);
    }
    __builtin_amdgcn_sched_barrier(0);  // keep A-loads ABOVE the staging (vmcnt count)
    if (t + 1 < n) {  // issue next B tile's staging, flies under compute
      const int jn = i0 + (t + 1) * 64;
#pragma unroll
      for (int q = 0; q < 4; ++q) {
        const int rr = (w * 4 + q) * 8 + srow;
        load_lds16(Brow + (size_t)rr * Tdim + (jn + schunk), &Bs[cur ^ 1][(w * 4 + q) * 512]);
      }
    }
#pragma unroll
    for (int kk = 0; kk < 2; ++kk) {
      bf16x8 bfr[4];
      const int chunk = kk * 4 + kq;
      const int slot = (chunk ^ (lr16 & 7)) * 8;   // un-swizzle
#pragma unroll
      for (int c = 0; c < 4; ++c)
        bfr[c] = *reinterpret_cast<const bf16x8*>(&Bs[cur][(wc * 64 + c * 16 + lr16) * 64 + slot]);
#pragma unroll
      for (int r = 0; r < 4; ++r)
#pragma unroll
        for (int c = 0; c < 4; ++c)
          acc[r][c] = __builtin_amdgcn_mfma_f32_16x16x32_bf16(af[kk][r], bfr[c], acc[r][c], 0, 0, 0);
    }
  }

  // fused epilogue: C/D layout col=lane&15 (m), row=(lane>>4)*4+reg (i).
  // out even = x even (exact fp32 passthrough), odd = phi*softplus(graw[m]).
  const int lr = l & 15;
  const int lq = l >> 4;
  float gm[4];
#pragma unroll
  for (int c = 0; c < 4; ++c) {
    const float v = graw[m0 + wc * 64 + c * 16 + lr];
    gm[c] = fmaxf(v, 0.0f) + __logf(1.0f + __expf(-fabsf(v)));  // stable softplus
  }
#pragma unroll
  for (int r = 0; r < 4; ++r) {
    const int ii = i0 + wr * 64 + r * 16 + lq * 4;
#pragma unroll
    for (int c = 0; c < 4; ++c) {
      const int m = m0 + wc * 64 + c * 16 + lr;
#pragma unroll
      for (int v = 0; v < 4; ++v) {
        const size_t o = ((size_t)(b * Tdim + ii + v)) * Edim + 2 * m;
        const float2 xv = *reinterpret_cast<const float2*>(&x[o]);
        float2 res;
        res.x = xv.x;
        res.y = acc[r][c][v] * gm[c];
        *reinterpret_cast<float2*>(&out[o]) = res;
      }
    }
  }
}

// ---------------- slow-but-correct fallback (only if ws too small) ----------------
__global__ __launch_bounds__(256) void fallback_kernel(const float* __restrict__ x,
                                                       const float* __restrict__ graw,
                                                       float* __restrict__ out) {
  const int i = blockIdx.x, b = blockIdx.y, tid = threadIdx.x;
  const float inv_h = 1.0f / (float)(Tdim - i);
  float s = 0.0f;
  for (int j = i + tid; j < Tdim; j += 256)
    s += kernel_g((float)(j - i), inv_h);
#pragma unroll
  for (int off = 32; off; off >>= 1) s += __shfl_down(s, off);
  __shared__ float red[4];
  __shared__ float sinv_sh;
  if ((tid & 63) == 0) red[tid >> 6] = s;
  __syncthreads();
  if (tid == 0) sinv_sh = 1.0f / (red[0] + red[1] + red[2] + red[3]);
  __syncthreads();
  const float sinv = sinv_sh;
  const float* xb = x + (size_t)b * Tdim * Edim;
  float a0 = 0.0f, a1 = 0.0f;
  const int m0 = tid, m1 = tid + 256;
  for (int j = i; j < Tdim; ++j) {
    const float wgt = kernel_g((float)(j - i), inv_h);
    const float* xr = xb + (size_t)j * Edim;
    a0 += wgt * xr[2 * m0];
    a1 += wgt * xr[2 * m1];
  }
  const float v0 = graw[m0], v1 = graw[m1];
  const float g0 = fmaxf(v0, 0.0f) + log1pf(__expf(-fabsf(v0)));
  const float g1 = fmaxf(v1, 0.0f) + log1pf(__expf(-fabsf(v1)));
  const size_t o = ((size_t)(b * Tdim + i)) * Edim;
  const float* xi = xb + (size_t)i * Edim;
  out[o + 2 * m0]     = xi[2 * m0];
  out[o + 2 * m0 + 1] = a0 * sinv * g0;
  out[o + 2 * m1]     = xi[2 * m1];
  out[o + 2 * m1 + 1] = a1 * sinv * g1;
}

extern "C" void kernel_launch(void* const* d_in, const int* in_sizes, int n_in,
                              void* d_out, int out_size, void* d_ws, size_t ws_size,
                              hipStream_t stream) {
  const float* x = (const float*)d_in[0];
  // d_in[1] is the triu mask: always upper-triangular by construction; folded analytically.
  const float* gate_raw = (const float*)d_in[2];
  float* out = (float*)d_out;

  const size_t XcT_bytes  = (size_t)Bdim * Mdim * Tdim * 2;   // 16 MiB
  const size_t Kswz_bytes = (size_t)NTILES * 16384;           // 16.5 MiB
  const size_t inv_bytes  = (size_t)Tdim * 4;                 // 16 KiB
  const size_t need = XcT_bytes + Kswz_bytes + inv_bytes;

  if (ws_size < need) {
    fallback_kernel<<<dim3(Tdim, Bdim), 256, 0, stream>>>(x, gate_raw, out);
    return;
  }

  char* ws = (char*)d_ws;
  unsigned short* XcT  = (unsigned short*)ws;
  unsigned short* Kswz = (unsigned short*)(ws + XcT_bytes);
  float* inv_s         = (float*)(ws + XcT_bytes + Kswz_bytes);

  prep_kernel<<<dim3(2 * Tdim), 256, 0, stream>>>(x, inv_s, XcT);
  packK_kernel<<<dim3(NTILES), 256, 0, stream>>>(inv_s, Kswz);
  gemm_kernel<<<dim3(512), 256, 0, stream>>>(Kswz, XcT, x, gate_raw, out);
}

// Round 4
// 221.578 us; speedup vs baseline: 1.1428x; 1.0268x over previous
//
#include <hip/hip_runtime.h>
#include <cstdint>
#include <cstddef>

// Problem constants (reference: B=4, T=4096, E=1024, M=E/2=512)
#define Tdim 4096
#define Bdim 4
#define Edim 1024
#define Mdim 512
#define EPSF 1e-6f
#define NTILES 1056  // sum over p of (64-2p) = S(32), panels store only k>=i0

typedef __bf16 bf16x8 __attribute__((ext_vector_type(8)));
typedef float f32x4 __attribute__((ext_vector_type(4)));

// S(p) = number of k64-tiles in panels [0,p) = p*(65-p)
__host__ __device__ __forceinline__ int panel_start(int p) { return p * (65 - p); }

// float -> bf16 bits, round-to-nearest-even (used in extract path)
__device__ __forceinline__ unsigned short f2bf(float f) {
  union { float f; unsigned int u; } a; a.f = f;
  unsigned int r = a.u + 0x7fffu + ((a.u >> 16) & 1u);
  return (unsigned short)(r >> 16);
}

// pack two f32 -> bf16x2 (round-half-up; 0.5-ulp bound, ties negligible here)
__device__ __forceinline__ unsigned int pack_bf16(float a, float b) {
  union { float f; unsigned int u; } ua, ub; ua.f = a; ub.f = b;
  // dst bytes [0,1,2,3] = [a.b2, a.b3, b.b2, b.b3]
  return __builtin_amdgcn_perm(ub.u + 0x8000u, ua.u + 0x8000u, 0x07060302u);
}

// bump kernel g(u) = exp(1 - 1/(1-u^2+eps)); reference's u>=1-EPS clamp can
// never fire for j<=T-1 (u_max = 1 - 1/horizon), so it is omitted.
__device__ __forceinline__ float kernel_g(float dj, float inv_h) {
  float u = fminf(dj * inv_h, 1.0f - EPSF);
  return __expf(1.0f - 1.0f / (1.0f - u * u + EPSF));
}

typedef void __attribute__((address_space(1)))* gas1;
typedef void __attribute__((address_space(3)))* las3;
// async global->LDS, 16B per lane; LDS dest = wave-uniform base + lane*16
__device__ __forceinline__ void load_lds16(const void* g, void* l) {
  __builtin_amdgcn_global_load_lds((gas1)(g), (las3)(l), 16, 0, 0);
}

// ---------------- prep: row sums (inv_s) AND Xc transpose ----------------
// grid 8192 x 256. Blocks [0,4096): rowsum only -- compute sum_j g(i,j),
// write inv_s[i] = 1/max(sum,eps). Blocks [4096,8192): extract tile ->
// XcT[b][m][j] = bf16(x[b][j][2m]). (R3-verified, unchanged.)
__global__ __launch_bounds__(256) void prep_kernel(const float* __restrict__ x,
                                                   float* __restrict__ inv_s,
                                                   unsigned short* __restrict__ XcT) {
  __shared__ float smem[1104];  // extract: [0..1087] as ushort[32][68]; rowsum: [1088..1091]
  const int tid = threadIdx.x;
  const int id = blockIdx.x;
  if (id < Tdim) {
    // ---- rowsum for K row i (same summation order as R0 -> identical bits) ----
    const int i = id;
    const float inv_h = __fdividef(1.0f, (float)(Tdim - i));
    float s = 0.0f;
    for (int j = i + tid; j < Tdim; j += 256)
      s += kernel_g((float)(j - i), inv_h);
#pragma unroll
    for (int off = 32; off; off >>= 1) s += __shfl_down(s, off);
    if ((tid & 63) == 0) smem[1088 + (tid >> 6)] = s;
    __syncthreads();
    if (tid == 0)
      inv_s[i] = __fdividef(
          1.0f, fmaxf(smem[1088] + smem[1089] + smem[1090] + smem[1091], EPSF));
  } else {
    // ---- extract tile: 64 j x 32 m ----
    const int eid = id - Tdim;
    const int j0 = (eid & 63) * 64;
    const int m0 = ((eid >> 6) & 15) * 32;
    const int b  = eid >> 10;
    unsigned short* Ls = reinterpret_cast<unsigned short*>(smem);  // [32][68]
    const int q = tid & 15;        // float4 chunk along e
    const int jbase = tid >> 4;    // 0..15
#pragma unroll
    for (int it = 0; it < 4; ++it) {
      const int jj = jbase + it * 16;
      const size_t off = ((size_t)(b * Tdim + j0 + jj)) * Edim + 2 * m0 + 4 * q;
      const float4 v = *reinterpret_cast<const float4*>(&x[off]);
      Ls[(2 * q) * 68 + jj]     = f2bf(v.x);   // even channel of m0+2q
      Ls[(2 * q + 1) * 68 + jj] = f2bf(v.z);   // even channel of m0+2q+1
    }
    __syncthreads();
    const int ch = tid & 15;
    const int mb = tid >> 4;
#pragma unroll
    for (int it = 0; it < 2; ++it) {
      const int m = mb + it * 16;
      ushort4 uv;
      uv.x = Ls[m * 68 + 4 * ch];
      uv.y = Ls[m * 68 + 4 * ch + 1];
      uv.z = Ls[m * 68 + 4 * ch + 2];
      uv.w = Ls[m * 68 + 4 * ch + 3];
      *reinterpret_cast<ushort4*>(
          &XcT[((size_t)(b * Mdim + m0 + m)) * Tdim + j0 + 4 * ch]) = uv;
    }
  }
}

// ---------------- packK: K in MFMA-fragment order (R3-verified, unchanged) --------
__global__ __launch_bounds__(256) void packK_kernel(const float* __restrict__ inv_s,
                                                    unsigned short* __restrict__ Kswz) {
  const int id = blockIdx.x;  // 0..NTILES-1
  int p = 0;
  while (id >= (p + 1) * (64 - p)) ++p;   // S(p+1) = (p+1)*(64-p)
  const int jt = id - panel_start(p);
  const int i0 = p * 128;
  const int jb0 = i0 + jt * 64;
  unsigned short* dst = Kswz + (size_t)id * 8192;  // 16 KB per (p,jt) tile
  const int tid = threadIdx.x;
#pragma unroll
  for (int ss = 0; ss < 4; ++ss) {
    const int G = ss * 256 + tid;          // chunk index 0..1023
    const int lane = G & 63;
    const int kk = (G >> 6) & 1;
    const int r  = (G >> 7) & 3;
    const int h  = G >> 9;
    const int li = h * 64 + r * 16 + (lane & 15);
    const int i  = i0 + li;
    const float inv_h = __fdividef(1.0f, (float)(Tdim - i));
    const float sinv = inv_s[i];
    const int jb = jb0 + (kk * 4 + (lane >> 4)) * 8;
    float v[8];
#pragma unroll
    for (int e = 0; e < 8; ++e) {
      const int j = jb + e;
      v[e] = (j >= i) ? kernel_g((float)(j - i), inv_h) * sinv : 0.0f;
    }
    uint4 pk;
    pk.x = pack_bf16(v[0], v[1]);
    pk.y = pack_bf16(v[2], v[3]);
    pk.z = pack_bf16(v[4], v[5]);
    pk.w = pack_bf16(v[6], v[7]);
    *reinterpret_cast<uint4*>(&dst[(size_t)G * 8]) = pk;
  }
}

// ---------------- GEMM: phi[b,i,m] = K[i,:] @ Xc[b,:,m], fused output write --------
// R3 structure with the K-loop latency chains broken (R3 measured 2650
// cyc/iter-pair vs ~515 throughput floor -- pure latency):
//  (1) A operand: 2-deep register ping-pong (af0/af1, loop hand-unrolled x2;
//      n = 64-2p is always even). A(t+1) is loaded during compute of t, so
//      its L2 latency hides under a full compute phase.
//  (2) B staging: 3 LDS buffers, depth 2, COUNTED vmcnt (T3+T4). Per iter:
//      stage B(t+2), `s_waitcnt vmcnt(12)` (A(t)x8 + B(t+2)x4 newest stay in
//      flight; everything older -- incl. B(t+1)'s staging -- complete), raw
//      s_barrier, sched_barrier(0). B-tile loads age TWO compute phases.
//      BK stays 64 (R2 showed doubling the barrier rate via BK=32 loses).
//  Issue counts are uniform 12 loads/wave/iter (tail issues clamped dummy
//  loads into dead buffers) so the vmcnt count is branch-free.
//  Buffer safety: at iter t, compute reads buf t%3, staging writes (t+2)%3,
//  outstanding B(t+1) sits in (t+1)%3 -- all distinct; buf (t+2)%3 held
//  B(t-1), whose ds_reads completed before iter t's barrier (MFMA lgkm waits
//  precede barrier arrival for every wave).
__global__ __launch_bounds__(256) void gemm_kernel(
    const unsigned short* __restrict__ Kswz,
    const unsigned short* __restrict__ XcT,
    const float* __restrict__ x,
    const float* __restrict__ graw,
    float* __restrict__ out) {
  __shared__ unsigned short Bs[3][128 * 64];  // XcT rows m0.., swizzled 16B slots
  const int id = blockIdx.x;           // 0..511
  int p;
  if (id < 256) p = id >> 4;
  else          p = 31 - ((id - 256) >> 4);
  const int mb = id & 15;
  const int i0 = p * 128;
  const int m0 = (mb & 3) * 128;
  const int b  = mb >> 2;
  const int tid = threadIdx.x;
  const int w = tid >> 6;
  const int l = tid & 63;
  const int wr = w >> 1, wc = w & 1;
  const unsigned short* Brow = XcT + ((size_t)b * Mdim + m0) * Tdim;
  const int srow  = l >> 3;                   // row within 8-row group
  const int sslot = l & 7;                    // linear 16B slot this lane fills
  const int schunk = (sslot ^ srow) * 8;      // swizzled source chunk (bf16 units)
  // A panel base for this wave's row-half and lane (units: shorts).
  // Fragment (r,kk) of k-tile t is at Apan + t*8192 + (r*2+kk)*512.
  const unsigned short* Apan =
      Kswz + (size_t)panel_start(p) * 8192 + (size_t)(wr * 8) * 512 + (size_t)l * 8;

  f32x4 acc[4][4] = {};
  const int n = (Tdim - i0) >> 6;  // 64 - 2p k64-tiles (even, >= 2)
  const int lr16 = l & 15;
  const int kq = l >> 4;  // 0..3: which 16B chunk quarter of the k-dim

  // ---- prologue. Issue order matters for the vmcnt count: B(0) FIRST (so
  // the first iter's vmcnt(12) forces it complete), then A(0), then B(1).
  // asm "" fences stop the compiler reordering loads across group edges.
#pragma unroll
  for (int q = 0; q < 4; ++q) {
    const int rr = (w * 4 + q) * 8 + srow;
    load_lds16(Brow + (size_t)rr * Tdim + (i0 + schunk), &Bs[0][(w * 4 + q) * 512]);
  }
  asm volatile("" ::: "memory");
  bf16x8 af0[2][4], af1[2][4];
#pragma unroll
  for (int r = 0; r < 4; ++r) {
    af0[0][r] = *reinterpret_cast<const bf16x8*>(Apan + (r * 2 + 0) * 512);
    af0[1][r] = *reinterpret_cast<const bf16x8*>(Apan + (r * 2 + 1) * 512);
  }
  asm volatile("" ::: "memory");
#pragma unroll
  for (int q = 0; q < 4; ++q) {
    const int rr = (w * 4 + q) * 8 + srow;
    load_lds16(Brow + (size_t)rr * Tdim + (i0 + 64 + schunk), &Bs[1][(w * 4 + q) * 512]);
  }

#define GHALF(tc, afC, afN)                                                       \
  do {                                                                            \
    asm volatile("s_waitcnt vmcnt(12)" ::: "memory");                             \
    __builtin_amdgcn_s_barrier();                                                 \
    __builtin_amdgcn_sched_barrier(0);                                            \
    /* prefetch A(tc+1) into afN (clamped dead load at tail) */                   \
    const int tpre = ((tc) + 1 < n) ? (tc) + 1 : n - 1;                           \
    const unsigned short* Ap = Apan + (size_t)tpre * 8192;                        \
    _Pragma("unroll")                                                             \
    for (int r = 0; r < 4; ++r) {                                                 \
      afN[0][r] = *reinterpret_cast<const bf16x8*>(Ap + (r * 2 + 0) * 512);       \
      afN[1][r] = *reinterpret_cast<const bf16x8*>(Ap + (r * 2 + 1) * 512);       \
    }                                                                             \
    /* stage B(tc+2) (clamped dead write at tail keeps vmcnt uniform) */          \
    {                                                                             \
      const int ts = (tc) + 2;                                                    \
      const int jn = i0 + (((ts) < n) ? (ts) : n - 1) * 64;                       \
      unsigned short* bdst = Bs[(ts) % 3];                                        \
      _Pragma("unroll")                                                           \
      for (int q = 0; q < 4; ++q) {                                               \
        const int rr = (w * 4 + q) * 8 + srow;                                    \
        load_lds16(Brow + (size_t)rr * Tdim + (jn + schunk),                      \
                   &bdst[(w * 4 + q) * 512]);                                     \
      }                                                                           \
    }                                                                             \
    /* compute tile tc from Bs[tc%3] + afC */                                     \
    {                                                                             \
      const unsigned short* bsrc = Bs[(tc) % 3];                                  \
      _Pragma("unroll")                                                           \
      for (int kk = 0; kk < 2; ++kk) {                                            \
        bf16x8 bfr[4];                                                            \
        const int chunk = kk * 4 + kq;                                            \
        const int slot = (chunk ^ (lr16 & 7)) * 8; /* un-swizzle */               \
        _Pragma("unroll")                                                         \
        for (int c = 0; c < 4; ++c)                                               \
          bfr[c] = *reinterpret_cast<const bf16x8*>(                              \
              &bsrc[(wc * 64 + c * 16 + lr16) * 64 + slot]);                      \
        _Pragma("unroll")                                                         \
        for (int r = 0; r < 4; ++r)                                               \
          _Pragma("unroll")                                                       \
          for (int c = 0; c < 4; ++c)                                             \
            acc[r][c] = __builtin_amdgcn_mfma_f32_16x16x32_bf16(                  \
                afC[kk][r], bfr[c], acc[r][c], 0, 0, 0);                          \
      }                                                                           \
    }                                                                             \
  } while (0)

  for (int t = 0; t < n; t += 2) {
    GHALF(t, af0, af1);
    GHALF(t + 1, af1, af0);
  }
#undef GHALF

  // fused epilogue: C/D layout col=lane&15 (m), row=(lane>>4)*4+reg (i).
  // out even = x even (exact fp32 passthrough), odd = phi*softplus(graw[m]).
  const int lr = l & 15;
  const int lq = l >> 4;
  float gm[4];
#pragma unroll
  for (int c = 0; c < 4; ++c) {
    const float v = graw[m0 + wc * 64 + c * 16 + lr];
    gm[c] = fmaxf(v, 0.0f) + __logf(1.0f + __expf(-fabsf(v)));  // stable softplus
  }
#pragma unroll
  for (int r = 0; r < 4; ++r) {
    const int ii = i0 + wr * 64 + r * 16 + lq * 4;
#pragma unroll
    for (int c = 0; c < 4; ++c) {
      const int m = m0 + wc * 64 + c * 16 + lr;
#pragma unroll
      for (int v = 0; v < 4; ++v) {
        const size_t o = ((size_t)(b * Tdim + ii + v)) * Edim + 2 * m;
        const float2 xv = *reinterpret_cast<const float2*>(&x[o]);
        float2 res;
        res.x = xv.x;
        res.y = acc[r][c][v] * gm[c];
        *reinterpret_cast<float2*>(&out[o]) = res;
      }
    }
  }
}

// ---------------- slow-but-correct fallback (only if ws too small) ----------------
__global__ __launch_bounds__(256) void fallback_kernel(const float* __restrict__ x,
                                                       const float* __restrict__ graw,
                                                       float* __restrict__ out) {
  const int i = blockIdx.x, b = blockIdx.y, tid = threadIdx.x;
  const float inv_h = 1.0f / (float)(Tdim - i);
  float s = 0.0f;
  for (int j = i + tid; j < Tdim; j += 256)
    s += kernel_g((float)(j - i), inv_h);
#pragma unroll
  for (int off = 32; off; off >>= 1) s += __shfl_down(s, off);
  __shared__ float red[4];
  __shared__ float sinv_sh;
  if ((tid & 63) == 0) red[tid >> 6] = s;
  __syncthreads();
  if (tid == 0) sinv_sh = 1.0f / (red[0] + red[1] + red[2] + red[3]);
  __syncthreads();
  const float sinv = sinv_sh;
  const float* xb = x + (size_t)b * Tdim * Edim;
  float a0 = 0.0f, a1 = 0.0f;
  const int m0 = tid, m1 = tid + 256;
  for (int j = i; j < Tdim; ++j) {
    const float wgt = kernel_g((float)(j - i), inv_h);
    const float* xr = xb + (size_t)j * Edim;
    a0 += wgt * xr[2 * m0];
    a1 += wgt * xr[2 * m1];
  }
  const float v0 = graw[m0], v1 = graw[m1];
  const float g0 = fmaxf(v0, 0.0f) + log1pf(__expf(-fabsf(v0)));
  const float g1 = fmaxf(v1, 0.0f) + log1pf(__expf(-fabsf(v1)));
  const size_t o = ((size_t)(b * Tdim + i)) * Edim;
  const float* xi = xb + (size_t)i * Edim;
  out[o + 2 * m0]     = xi[2 * m0];
  out[o + 2 * m0 + 1] = a0 * sinv * g0;
  out[o + 2 * m1]     = xi[2 * m1];
  out[o + 2 * m1 + 1] = a1 * sinv * g1;
}

extern "C" void kernel_launch(void* const* d_in, const int* in_sizes, int n_in,
                              void* d_out, int out_size, void* d_ws, size_t ws_size,
                              hipStream_t stream) {
  const float* x = (const float*)d_in[0];
  // d_in[1] is the triu mask: always upper-triangular by construction; folded analytically.
  const float* gate_raw = (const float*)d_in[2];
  float* out = (float*)d_out;

  const size_t XcT_bytes  = (size_t)Bdim * Mdim * Tdim * 2;   // 16 MiB
  const size_t Kswz_bytes = (size_t)NTILES * 16384;           // 16.5 MiB
  const size_t inv_bytes  = (size_t)Tdim * 4;                 // 16 KiB
  const size_t need = XcT_bytes + Kswz_bytes + inv_bytes;

  if (ws_size < need) {
    fallback_kernel<<<dim3(Tdim, Bdim), 256, 0, stream>>>(x, gate_raw, out);
    return;
  }

  char* ws = (char*)d_ws;
  unsigned short* XcT  = (unsigned short*)ws;
  unsigned short* Kswz = (unsigned short*)(ws + XcT_bytes);
  float* inv_s         = (float*)(ws + XcT_bytes + Kswz_bytes);

  prep_kernel<<<dim3(2 * Tdim), 256, 0, stream>>>(x, inv_s, XcT);
  packK_kernel<<<dim3(NTILES), 256, 0, stream>>>(inv_s, Kswz);
  gemm_kernel<<<dim3(512), 256, 0, stream>>>(Kswz, XcT, x, gate_raw, out);
}